// Round 9
// baseline (207.757 us; speedup 1.0000x reference)
//
#include <hip/hip_runtime.h>

typedef unsigned short u16;
typedef __bf16 bf16_t;
typedef __bf16 bf16x8 __attribute__((ext_vector_type(8)));
typedef float f32x4 __attribute__((ext_vector_type(4)));

#define B_DIM 4096
#define D_DIM 1024
#define TT    32   // 128-wide tiles per dim
#define NT    16   // K-tiles (1024 / 64)
#define NSLOT 66   // rowacc: 2*tj+wc (0..63); colacc diag: 64+wr

// Fully fused kernel: f32 load -> exact fp32 row-norms (accumulated across
// K-loop) + bf16 convert -> swizzled LDS -> MFMA GEMM (upper-tri tiles only)
// -> cos/temp/exp epilogue -> deterministic per-(block,wave) partial slots.
// No atomics, no pre-zeroing, no separate norm pass.
__global__ __launch_bounds__(256, 2) void gemm_fused_kernel(
        const float* __restrict__ Lf, const float* __restrict__ Rf,
        float* __restrict__ part, float* __restrict__ diag) {
    __shared__ __align__(16) u16 Ls[2][128 * 64];   // swizzled bf16 tiles
    __shared__ __align__(16) u16 Rs[2][128 * 64];
    __shared__ float nA[128], nB[128];              // row norms (published)

    // XCD-aware bijective swizzle (528 = 8 * 66)
    int bid = (int)blockIdx.x;
    int swz = (bid & 7) * 66 + (bid >> 3);
    int b = swz, ti = 0;
    while (b >= TT - ti) { b -= TT - ti; ++ti; }
    const int tj = ti + b;
    const int brow = ti * 128, bcol = tj * 128;
    const bool diagblk = (ti == tj);

    const int tid  = threadIdx.x;
    const int lane = tid & 63;
    const int wave = tid >> 6;   // 0..3
    const int wr   = wave >> 1;  // row half
    const int wc   = wave & 1;   // col half
    const int fr   = lane & 15;

    // staging geometry: thread covers rows {p*32 + srow}, col-chunk sc (8 f32)
    const int srow = tid >> 3;            // 0..31
    const int sc   = tid & 7;             // 0..7
    const int swcs = sc ^ (srow & 7);     // swizzled chunk slot (row&7 == srow&7)

    const float* pA = Lf + (size_t)brow * D_DIM;
    const float* pB = Rf + (size_t)bcol * D_DIM;

    float4 ga[8], gb[8];
    float ssA[4] = {0.f, 0.f, 0.f, 0.f};
    float ssB[4] = {0.f, 0.f, 0.f, 0.f};
    f32x4 acc[4][4] = {};

#define LOADREGS(k0)                                                         \
    do {                                                                     \
        _Pragma("unroll")                                                    \
        for (int p = 0; p < 4; ++p) {                                        \
            const float* a = pA + (size_t)(p * 32 + srow) * D_DIM + (k0) + sc * 8; \
            ga[2 * p]     = *reinterpret_cast<const float4*>(a);             \
            ga[2 * p + 1] = *reinterpret_cast<const float4*>(a + 4);         \
            const float* bp = pB + (size_t)(p * 32 + srow) * D_DIM + (k0) + sc * 8; \
            gb[2 * p]     = *reinterpret_cast<const float4*>(bp);            \
            gb[2 * p + 1] = *reinterpret_cast<const float4*>(bp + 4);        \
        }                                                                    \
    } while (0)

#define CVTWRITE(buf)                                                        \
    do {                                                                     \
        _Pragma("unroll")                                                    \
        for (int p = 0; p < 4; ++p) {                                        \
            float4 x = ga[2 * p], y = ga[2 * p + 1];                         \
            ssA[p] += x.x * x.x + x.y * x.y + x.z * x.z + x.w * x.w          \
                    + y.x * y.x + y.y * y.y + y.z * y.z + y.w * y.w;         \
            bf16x8 v;                                                        \
            v[0] = (bf16_t)x.x; v[1] = (bf16_t)x.y;                          \
            v[2] = (bf16_t)x.z; v[3] = (bf16_t)x.w;                          \
            v[4] = (bf16_t)y.x; v[5] = (bf16_t)y.y;                          \
            v[6] = (bf16_t)y.z; v[7] = (bf16_t)y.w;                          \
            *reinterpret_cast<bf16x8*>(                                      \
                &Ls[buf][(p * 32 + srow) * 64 + swcs * 8]) = v;              \
            x = gb[2 * p]; y = gb[2 * p + 1];                                \
            ssB[p] += x.x * x.x + x.y * x.y + x.z * x.z + x.w * x.w          \
                    + y.x * y.x + y.y * y.y + y.z * y.z + y.w * y.w;         \
            v[0] = (bf16_t)x.x; v[1] = (bf16_t)x.y;                          \
            v[2] = (bf16_t)x.z; v[3] = (bf16_t)x.w;                          \
            v[4] = (bf16_t)y.x; v[5] = (bf16_t)y.y;                          \
            v[6] = (bf16_t)y.z; v[7] = (bf16_t)y.w;                          \
            *reinterpret_cast<bf16x8*>(                                      \
                &Rs[buf][(p * 32 + srow) * 64 + swcs * 8]) = v;              \
        }                                                                    \
    } while (0)

#define COMPUTE(buf)                                                         \
    do {                                                                     \
        _Pragma("unroll")                                                    \
        for (int kk = 0; kk < 2; ++kk) {                                     \
            bf16x8 af[4], bfr[4];                                            \
            _Pragma("unroll")                                                \
            for (int m = 0; m < 4; ++m) {                                    \
                int row = wr * 64 + m * 16 + fr;                             \
                int cs = ((kk << 2) | (lane >> 4)) ^ (row & 7);              \
                af[m] = *reinterpret_cast<const bf16x8*>(                    \
                    &Ls[buf][row * 64 + cs * 8]);                            \
            }                                                                \
            _Pragma("unroll")                                                \
            for (int n = 0; n < 4; ++n) {                                    \
                int row = wc * 64 + n * 16 + fr;                             \
                int cs = ((kk << 2) | (lane >> 4)) ^ (row & 7);              \
                bfr[n] = *reinterpret_cast<const bf16x8*>(                   \
                    &Rs[buf][row * 64 + cs * 8]);                            \
            }                                                                \
            _Pragma("unroll")                                                \
            for (int m = 0; m < 4; ++m)                                      \
                _Pragma("unroll")                                            \
                for (int n = 0; n < 4; ++n)                                  \
                    acc[m][n] = __builtin_amdgcn_mfma_f32_16x16x32_bf16(     \
                        af[m], bfr[n], acc[m][n], 0, 0, 0);                  \
        }                                                                    \
    } while (0)

    // prologue: tile 0 through regs into buf 0
    LOADREGS(0);
    CVTWRITE(0);
    __syncthreads();

    int cur = 0;
    for (int t = 0; t < NT; ++t) {
        if (t + 1 < NT) LOADREGS((t + 1) * 64);   // prefetch t+1 (in flight)
        COMPUTE(cur);                             // hides the load latency
        if (t + 1 < NT) CVTWRITE(cur ^ 1);        // waits arrive post-MFMA
        __syncthreads();                          // writes visible, reads done
        cur ^= 1;
    }

    // publish exact fp32 row norms (reduce across the 8 threads per row)
    #pragma unroll
    for (int p = 0; p < 4; ++p) {
        float sa = ssA[p], sb = ssB[p];
        sa += __shfl_xor(sa, 1); sa += __shfl_xor(sa, 2); sa += __shfl_xor(sa, 4);
        sb += __shfl_xor(sb, 1); sb += __shfl_xor(sb, 2); sb += __shfl_xor(sb, 4);
        if (sc == 0) {
            nA[p * 32 + srow] = sqrtf(sa);
            nB[p * 32 + srow] = sqrtf(sb);
        }
    }
    __syncthreads();

    // --- epilogue: cos -> /T -> exp -> deterministic partial slots ---
    // C/D layout: col = lane&15, row = (lane>>4)*4 + r
    const int fcol  = lane & 15;
    const int frow0 = (lane >> 4) * 4;

    float rnj[4];
    #pragma unroll
    for (int n = 0; n < 4; ++n)
        rnj[n] = nB[wc * 64 + n * 16 + fcol];

    float colacc[4] = {0.f, 0.f, 0.f, 0.f};

    #pragma unroll
    for (int m = 0; m < 4; ++m) {
        #pragma unroll
        for (int r = 0; r < 4; ++r) {
            const int li = wr * 64 + m * 16 + frow0 + r;
            const int i  = brow + li;
            const float lni = nA[li];
            float rowacc = 0.f;
            #pragma unroll
            for (int n = 0; n < 4; ++n) {
                const int j = bcol + wc * 64 + n * 16 + fcol;
                const float denom = fmaxf(lni * rnj[n], 1e-8f);
                const float v = acc[m][n][r] * 10.0f / denom;
                if (diagblk && i == j) diag[i] = v;
                const float e = __expf(v);
                if (i <= j) rowacc += e;
                if (i < j)  colacc[n] += e;
            }
            rowacc += __shfl_xor(rowacc, 1);
            rowacc += __shfl_xor(rowacc, 2);
            rowacc += __shfl_xor(rowacc, 4);
            rowacc += __shfl_xor(rowacc, 8);
            // slot 2*tj+wc unique per (row i, this block, this wave)
            if (fcol == 0) part[(size_t)(2 * tj + wc) * B_DIM + i] = rowacc;
        }
    }
    #pragma unroll
    for (int n = 0; n < 4; ++n) {
        float c = colacc[n];
        c += __shfl_xor(c, 16);
        c += __shfl_xor(c, 32);
        if (lane < 16) {
            const int j = bcol + wc * 64 + n * 16 + fcol;
            const int slot = diagblk ? (64 + wr) : (2 * ti + wr);
            part[(size_t)slot * B_DIM + j] = c;
        }
    }
#undef LOADREGS
#undef CVTWRITE
#undef COMPUTE
}

// loss = mean_i( log( sum_slots part[s][i] ) - diag[i] )
// Every slot 0..65 is written for every row (coverage proof: for row-tile T,
// rowacc fills slots 2T..63, colacc fills 0..2T-1, diag colacc fills 64,65).
__global__ __launch_bounds__(1024) void final_loss_kernel(
        const float* __restrict__ part, const float* __restrict__ diag,
        float* __restrict__ out) {
    float s = 0.f;
    for (int i = threadIdx.x; i < B_DIM; i += 1024) {
        float rs = 0.f;
        #pragma unroll
        for (int k = 0; k < NSLOT; ++k)
            rs += part[(size_t)k * B_DIM + i];
        s += logf(rs) - diag[i];
    }
    __shared__ float red[16];
    #pragma unroll
    for (int off = 32; off > 0; off >>= 1) s += __shfl_down(s, off);
    if ((threadIdx.x & 63) == 0) red[threadIdx.x >> 6] = s;
    __syncthreads();
    if (threadIdx.x == 0) {
        float tot = 0.f;
        #pragma unroll
        for (int k = 0; k < 16; ++k) tot += red[k];
        out[0] = tot / (float)B_DIM;
    }
}

extern "C" void kernel_launch(void* const* d_in, const int* in_sizes, int n_in,
                              void* d_out, int out_size, void* d_ws, size_t ws_size,
                              hipStream_t stream) {
    const float* L = (const float*)d_in[0];
    const float* R = (const float*)d_in[1];

    char* ws = (char*)d_ws;
    float* part = (float*)ws;                                  // 66*4096 f32
    float* diag = (float*)(ws + (size_t)NSLOT * B_DIM * sizeof(float));

    const int nblocks = TT * (TT + 1) / 2;   // 528 upper-triangular tiles
    gemm_fused_kernel<<<nblocks, 256, 0, stream>>>(L, R, part, diag);
    final_loss_kernel<<<1, 1024, 0, stream>>>(part, diag, (float*)d_out);
}

// Round 11
// 127.062 us; speedup vs baseline: 1.6351x; 1.6351x over previous
//
#include <hip/hip_runtime.h>

typedef unsigned short u16;
typedef __bf16 bf16x8 __attribute__((ext_vector_type(8)));
typedef float f32x4 __attribute__((ext_vector_type(4)));

#define B_DIM 4096
#define D_DIM 1024
#define TT    64   // 64-wide tiles per dim
#define NT    16   // K-tiles (1024 / 64)
#define NSLOT 130  // row: 2*tj+wc (0..127); diag col: 128+wr

#define GLOAD_LDS16(g, l)                                            \
    __builtin_amdgcn_global_load_lds(                                \
        (const __attribute__((address_space(1))) void*)(g),          \
        (__attribute__((address_space(3))) void*)(l), 16, 0, 0)

__device__ inline u16 f2bf(float f) {
    union { float f; unsigned u; } x; x.f = f;
    unsigned u = x.u;
    return (u16)((u + 0x7fffu + ((u >> 16) & 1u)) >> 16);  // RNE
}

// 1 wave per row, 4 rows per block; grid = 2*B/4.
// fp32 row L2-norm (exact, matches reference) + bf16 conversion.
__global__ __launch_bounds__(256) void norm_convert_kernel(
        const float* __restrict__ L, const float* __restrict__ R,
        u16* __restrict__ Lbf, u16* __restrict__ Rbf,
        float* __restrict__ ln, float* __restrict__ rn) {
    const int wave = threadIdx.x >> 6;
    const int lane = threadIdx.x & 63;
    int g = blockIdx.x * 4 + wave;          // 0 .. 2*B-1
    const float* in; u16* outb; float* nout; int row;
    if (g < B_DIM) { in = L; outb = Lbf; nout = ln; row = g; }
    else           { in = R; outb = Rbf; nout = rn; row = g - B_DIM; }

    const float4* r4 = reinterpret_cast<const float4*>(in + (size_t)row * D_DIM);
    ushort4* o4 = reinterpret_cast<ushort4*>(outb + (size_t)row * D_DIM);
    float ss = 0.f;
    #pragma unroll
    for (int c = 0; c < 4; ++c) {
        float4 v = r4[lane + 64 * c];
        ss += v.x * v.x + v.y * v.y + v.z * v.z + v.w * v.w;
        ushort4 o;
        o.x = f2bf(v.x); o.y = f2bf(v.y); o.z = f2bf(v.z); o.w = f2bf(v.w);
        o4[lane + 64 * c] = o;
    }
    #pragma unroll
    for (int off = 32; off > 0; off >>= 1) ss += __shfl_xor(ss, off);
    if (lane == 0) nout[row] = sqrtf(ss);
}

// 64x64-tile bf16 MFMA GEMM (upper-tri tiles), counted-vmcnt double-buffered
// K-loop, fused exp epilogue writing deterministic partial slots (no atomics).
// 2080 blocks, 32 KiB LDS -> many co-resident blocks/CU for latency hiding.
__global__ __launch_bounds__(256, 4) void gemm_fused_kernel(
        const u16* __restrict__ Lbf, const u16* __restrict__ Rbf,
        const float* __restrict__ ln, const float* __restrict__ rn,
        float* __restrict__ part, float* __restrict__ diag) {
    __shared__ __align__(16) u16 Ls[2][64 * 64];   // 8 KiB per buf
    __shared__ __align__(16) u16 Rs[2][64 * 64];

    // XCD-aware bijective swizzle (2080 = 8 * 260)
    int bid = (int)blockIdx.x;
    int swz = (bid & 7) * 260 + (bid >> 3);
    int b = swz, ti = 0;
    while (b >= TT - ti) { b -= TT - ti; ++ti; }
    const int tj = ti + b;
    const int brow = ti * 64, bcol = tj * 64;
    const bool diagblk = (ti == tj);

    const int tid  = threadIdx.x;
    const int lane = tid & 63;
    const int wave = tid >> 6;   // 0..3
    const int wr   = wave >> 1;  // row half (32 rows)
    const int wc   = wave & 1;   // col half (32 cols)
    const int fr   = lane & 15;

    // staging: per wave 2 gloads for A + 2 for B; each gload = 64 lanes x 16B
    // = 8 rows x 128B. Global source pre-swizzled (chunk ^ (row&7)); LDS linear.
    const int l8 = lane >> 3;   // row within 8-row group (== row&7)
    const int c8 = lane & 7;    // 16B chunk slot within row
    size_t gA[2], gB[2];
    int ldsOff[2];
    #pragma unroll
    for (int s = 0; s < 2; ++s) {
        int row = wave * 16 + s * 8 + l8;
        int chunk = c8 ^ l8;
        gA[s] = (size_t)(brow + row) * D_DIM + chunk * 8;
        gB[s] = (size_t)(bcol + row) * D_DIM + chunk * 8;
        ldsOff[s] = (wave * 16 + s * 8) * 64;   // wave-uniform
    }

#define STAGE(buf, k0)                                               \
    do {                                                             \
        _Pragma("unroll")                                            \
        for (int s = 0; s < 2; ++s) {                                \
            GLOAD_LDS16(Lbf + gA[s] + (k0), &Ls[buf][ldsOff[s]]);    \
            GLOAD_LDS16(Rbf + gB[s] + (k0), &Rs[buf][ldsOff[s]]);    \
        }                                                            \
    } while (0)

    f32x4 acc[2][2] = {};

#define COMPUTE(buf)                                                  \
    do {                                                              \
        _Pragma("unroll")                                             \
        for (int kk = 0; kk < 2; ++kk) {                              \
            bf16x8 af[2], bfr[2];                                     \
            _Pragma("unroll")                                         \
            for (int m = 0; m < 2; ++m) {                             \
                int row = wr * 32 + m * 16 + fr;                      \
                int cs = ((kk << 2) | (lane >> 4)) ^ (row & 7);       \
                af[m] = *reinterpret_cast<const bf16x8*>(             \
                    &Ls[buf][row * 64 + cs * 8]);                     \
            }                                                         \
            _Pragma("unroll")                                         \
            for (int n = 0; n < 2; ++n) {                             \
                int row = wc * 32 + n * 16 + fr;                      \
                int cs = ((kk << 2) | (lane >> 4)) ^ (row & 7);       \
                bfr[n] = *reinterpret_cast<const bf16x8*>(            \
                    &Rs[buf][row * 64 + cs * 8]);                     \
            }                                                         \
            _Pragma("unroll")                                         \
            for (int m = 0; m < 2; ++m)                               \
                _Pragma("unroll")                                     \
                for (int n = 0; n < 2; ++n)                           \
                    acc[m][n] = __builtin_amdgcn_mfma_f32_16x16x32_bf16( \
                        af[m], bfr[n], acc[m][n], 0, 0, 0);           \
        }                                                             \
    } while (0)

    // prologue: stage K-tile 0 into buf 0 (4 loads/wave in flight)
    STAGE(0, 0);

    int cur = 0;
    for (int t = 0; t < NT; ++t) {
        if (t + 1 < NT) {
            STAGE(cur ^ 1, (t + 1) * 64);   // 8/wave in flight (t and t+1)
            // wait ONLY for tile t's 4 loads; t+1's 4 keep flying
            asm volatile("s_waitcnt vmcnt(4)" ::: "memory");
        } else {
            asm volatile("s_waitcnt vmcnt(0)" ::: "memory");
        }
        __builtin_amdgcn_s_barrier();       // buf cur fully staged
        asm volatile("" ::: "memory");
        COMPUTE(cur);
        asm volatile("" ::: "memory");      // keep ds_reads before next barrier
        __builtin_amdgcn_s_barrier();       // done reading cur
        cur ^= 1;
    }

    // --- epilogue: cos -> /T -> exp -> deterministic partial slots ---
    // C/D layout: col = lane&15, row = (lane>>4)*4 + r
    const int fcol  = lane & 15;
    const int frow0 = (lane >> 4) * 4;

    float rnj[2];
    #pragma unroll
    for (int n = 0; n < 2; ++n)
        rnj[n] = rn[bcol + wc * 32 + n * 16 + fcol];

    float colacc[2] = {0.f, 0.f};

    #pragma unroll
    for (int m = 0; m < 2; ++m) {
        #pragma unroll
        for (int r = 0; r < 4; ++r) {
            const int i = brow + wr * 32 + m * 16 + frow0 + r;
            const float lni = ln[i];
            float rowacc = 0.f;
            #pragma unroll
            for (int n = 0; n < 2; ++n) {
                const int j = bcol + wc * 32 + n * 16 + fcol;
                const float denom = fmaxf(lni * rnj[n], 1e-8f);
                const float v = acc[m][n][r] * 10.0f / denom;
                if (diagblk && i == j) diag[i] = v;
                const float e = __expf(v);
                if (i <= j) rowacc += e;
                if (i < j)  colacc[n] += e;
            }
            rowacc += __shfl_xor(rowacc, 1);
            rowacc += __shfl_xor(rowacc, 2);
            rowacc += __shfl_xor(rowacc, 4);
            rowacc += __shfl_xor(rowacc, 8);
            // slot unique per (row i, block, wave): 2*tj+wc in [2*ti, 128)
            if (fcol == 0) part[(size_t)(2 * tj + wc) * B_DIM + i] = rowacc;
        }
    }
    #pragma unroll
    for (int n = 0; n < 2; ++n) {
        float c = colacc[n];
        c += __shfl_xor(c, 16);
        c += __shfl_xor(c, 32);
        if (lane < 16) {
            const int j = bcol + wc * 32 + n * 16 + fcol;
            const int slot = diagblk ? (128 + wr) : (2 * ti + wr);
            part[(size_t)slot * B_DIM + j] = c;
        }
    }
#undef STAGE
#undef COMPUTE
}

// stage 1: 16 blocks x 256 rows: partial[b] = sum_i (log(sum_k part[k][i]) - diag[i])
__global__ __launch_bounds__(256) void loss_stage1_kernel(
        const float* __restrict__ part, const float* __restrict__ diag,
        float* __restrict__ partial) {
    const int i = blockIdx.x * 256 + threadIdx.x;
    float rs = 0.f;
    #pragma unroll 10
    for (int k = 0; k < NSLOT; ++k)
        rs += part[(size_t)k * B_DIM + i];
    float s = logf(rs) - diag[i];
    #pragma unroll
    for (int off = 32; off > 0; off >>= 1) s += __shfl_down(s, off);
    __shared__ float red[4];
    if ((threadIdx.x & 63) == 0) red[threadIdx.x >> 6] = s;
    __syncthreads();
    if (threadIdx.x == 0)
        partial[blockIdx.x] = red[0] + red[1] + red[2] + red[3];
}

// stage 2: single tiny block
__global__ __launch_bounds__(64) void loss_stage2_kernel(
        const float* __restrict__ partial, float* __restrict__ out) {
    float s = (threadIdx.x < 16) ? partial[threadIdx.x] : 0.f;
    #pragma unroll
    for (int off = 8; off > 0; off >>= 1) s += __shfl_down(s, off);
    if (threadIdx.x == 0) out[0] = s / (float)B_DIM;
}

extern "C" void kernel_launch(void* const* d_in, const int* in_sizes, int n_in,
                              void* d_out, int out_size, void* d_ws, size_t ws_size,
                              hipStream_t stream) {
    const float* L = (const float*)d_in[0];
    const float* R = (const float*)d_in[1];

    char* ws = (char*)d_ws;
    size_t o = 0;
    u16* Lbf     = (u16*)(ws + o);   o += (size_t)B_DIM * D_DIM * sizeof(u16);
    u16* Rbf     = (u16*)(ws + o);   o += (size_t)B_DIM * D_DIM * sizeof(u16);
    float* ln    = (float*)(ws + o); o += (size_t)B_DIM * sizeof(float);
    float* rn    = (float*)(ws + o); o += (size_t)B_DIM * sizeof(float);
    float* part  = (float*)(ws + o); o += (size_t)NSLOT * B_DIM * sizeof(float);
    float* diag  = (float*)(ws + o); o += (size_t)B_DIM * sizeof(float);
    float* partial = (float*)(ws + o); o += 16 * sizeof(float);

    norm_convert_kernel<<<2 * B_DIM / 4, 256, 0, stream>>>(L, R, Lbf, Rbf, ln, rn);

    const int nblocks = TT * (TT + 1) / 2;   // 2080 upper-triangular tiles
    gemm_fused_kernel<<<nblocks, 256, 0, stream>>>(Lbf, Rbf, ln, rn, part, diag);

    loss_stage1_kernel<<<16, 256, 0, stream>>>(part, diag, partial);
    loss_stage2_kernel<<<1, 64, 0, stream>>>(partial, (float*)d_out);
}